// Round 12
// baseline (652.801 us; speedup 1.0000x reference)
//
#include <hip/hip_runtime.h>
#include <math.h>

typedef _Float16 half8 __attribute__((ext_vector_type(8)));
typedef _Float16 half4t __attribute__((ext_vector_type(4)));
typedef float floatx4 __attribute__((ext_vector_type(4)));

// ============================================================================
// ConvDesc
// ============================================================================
struct ConvDesc {
  int HI, WI;
  int CIs;
  int OYs, OXs;
  int SXY;
  int osxy;
  int HO, WO;
  int CO_pad, CO_real, CO_store;
  int nclass;
  int py[4], px[4], nt[4];
  int tt[4][9], tdy[4][9], tdx[4][9];
};

#define STAT_SLOTS 16

// ============================================================================
// conv_gemm<BM,BN>: dbuf K-loop + fused BN-stats + LDS-transpose vectorized
// epilogue (half8 coalesced stores instead of 2B scalar stores).
// ============================================================================
template<int BM, int BN>
__global__ __launch_bounds__(256) void conv_gemm(
    const _Float16* __restrict__ act, const _Float16* __restrict__ wB,
    const float* __restrict__ bias, _Float16* __restrict__ y,
    float* __restrict__ stats, ConvDesc d)
{
  constexpr int WM = BM / 2, WN = BN / 2, FM = WM / 16, FN = WN / 16;
  constexpr int ARPT = BM / 64, BT = BN / 64;
  constexpr int AP = BM * 8 + 8;
  constexpr int ASZ = 4 * AP;
  constexpr int BSZ = BT * 2048;
  constexpr int OP = BN + 8;                 // output tile pitch (halfs)
  constexpr int KSZ = 2 * (ASZ + BSZ);
  constexpr int TSZ = BM * OP;
  constexpr int SMEMH = (KSZ > TSZ) ? KSZ : TSZ;
  __shared__ __align__(16) _Float16 smem[SMEMH];
  _Float16* As = smem;
  _Float16* Bs = smem + 2 * ASZ;

  const int tid = threadIdx.x;
  const int cls = blockIdx.z;
  const int m0 = blockIdx.x * BM, n0 = blockIdx.y * BN;
  const int q = tid & 3, r0 = tid >> 2;

  int aih[ARPT], aiw[ARPT], abase[ARPT];
  #pragma unroll
  for (int i = 0; i < ARPT; i++) {
    int p = m0 + r0 + i * 64;
    int n  = p >> (d.OYs + d.OXs);
    int oy = (p >> d.OXs) & ((1 << d.OYs) - 1);
    int ox = p & ((1 << d.OXs) - 1);
    aih[i] = oy * d.SXY;
    aiw[i] = ox * d.SXY;
    abase[i] = n * d.HI;
  }

  floatx4 acc[FM][FN] = {};
  const int wv = tid >> 6, lane = tid & 63;
  const int wm = wv >> 1, wn = wv & 1;
  const int fr = lane >> 4, fc = lane & 15;
  const int c5s = d.CIs - 5;
  const int c5m = (1 << c5s) - 1;
  const int kiters = d.nt[cls] << c5s;

  auto stageK = [&](int kk, int buf) {
    int ti = kk >> c5s, c5 = kk & c5m;
    int dy = d.tdy[cls][ti], dx = d.tdx[cls][ti];
    int kt0 = d.tt[cls][ti] << c5s;
    int c0 = c5 << 5;
    #pragma unroll
    for (int i = 0; i < ARPT; i++) {
      int ih = aih[i] + dy, iw = aiw[i] + dx;
      half8 v = {};
      if ((unsigned)ih < (unsigned)d.HI && (unsigned)iw < (unsigned)d.WI)
        v = *(const half8*)(act + ((((size_t)(abase[i] + ih)) * d.WI + iw) << d.CIs) + c0 + q * 8);
      *(half8*)(As + buf * ASZ + q * AP + (r0 + i * 64) * 8) = v;
    }
    #pragma unroll
    for (int j = 0; j < BT; j++) {
      const _Float16* src = wB + (size_t)((kt0 + c5) * (d.CO_pad >> 6) + (n0 >> 6) + j) * 2048 + tid * 8;
      *(half8*)(Bs + buf * BSZ + j * 2048 + tid * 8) = *(const half8*)src;
    }
  };

  stageK(0, 0);
  for (int kk = 0; kk < kiters; kk++) {
    __syncthreads();
    if (kk + 1 < kiters) stageK(kk + 1, (kk + 1) & 1);
    const int buf = kk & 1;
    half8 af[FM], bf[FN];
    #pragma unroll
    for (int a = 0; a < FM; a++)
      af[a] = *(const half8*)(As + buf * ASZ + fr * AP + (wm * WM + a * 16 + fc) * 8);
    #pragma unroll
    for (int b = 0; b < FN; b++) {
      int col = wn * WN + b * 16 + fc;
      bf[b] = *(const half8*)(Bs + buf * BSZ + (col >> 6) * 2048 + fr * 512 + (col & 63) * 8);
    }
    #pragma unroll
    for (int a = 0; a < FM; a++)
      #pragma unroll
      for (int b = 0; b < FN; b++)
        acc[a][b] = __builtin_amdgcn_mfma_f32_16x16x32_f16(af[a], bf[b], acc[a][b], 0, 0, 0);
  }

  // ---- epilogue: bias + stats + LDS transpose + coalesced half8 stores ----
  float bv[FN];
  #pragma unroll
  for (int b = 0; b < FN; b++) {
    int col = n0 + wn * WN + b * 16 + fc;
    bv[b] = (col < d.CO_real) ? bias[col] : 0.f;
  }
  float ssum[FN] = {}, ssq[FN] = {};
  __syncthreads();
  #pragma unroll
  for (int a = 0; a < FM; a++) {
    #pragma unroll
    for (int rr = 0; rr < 4; rr++) {
      int row = wm * WM + a * 16 + fr * 4 + rr;
      #pragma unroll
      for (int b = 0; b < FN; b++) {
        float val = acc[a][b][rr] + bv[b];
        smem[row * OP + wn * WN + b * 16 + fc] = (_Float16)val;
        ssum[b] += val; ssq[b] += val * val;
      }
    }
  }
  __syncthreads();
  constexpr int V = (BM * BN) / 2048;
  const int pyc = d.py[cls], pxc = d.px[cls];
  #pragma unroll
  for (int i = 0; i < V; i++) {
    int idx = i * 256 + tid;
    int row = idx / (BN / 8), cg = idx % (BN / 8);
    half8 v = *(const half8*)(smem + row * OP + cg * 8);
    int m = m0 + row;
    int n  = m >> (d.OYs + d.OXs);
    int oy = (m >> d.OXs) & ((1 << d.OYs) - 1);
    int ox = m & ((1 << d.OXs) - 1);
    size_t opix = ((size_t)(n * d.HO + oy * d.osxy + pyc)) * d.WO + ox * d.osxy + pxc;
    if (n0 + cg * 8 < d.CO_store)
      *(half8*)(y + opix * d.CO_store + n0 + cg * 8) = v;
  }
  __syncthreads();
  float2* red = (float2*)smem;
  #pragma unroll
  for (int b = 0; b < FN; b++)
    red[(wn * WN + b * 16 + fc) * 8 + wm * 4 + fr] = make_float2(ssum[b], ssq[b]);
  __syncthreads();
  if (tid < BN) {
    float s = 0.f, qv = 0.f;
    #pragma unroll
    for (int g2 = 0; g2 < 8; g2++) { float2 v = red[tid * 8 + g2]; s += v.x; qv += v.y; }
    int slot = (blockIdx.x + blockIdx.z) & (STAT_SLOTS - 1);
    float* sp = stats + ((size_t)(n0 + tid) * STAT_SLOTS + slot) * 2;
    atomicAdd(sp, s); atomicAdd(sp + 1, qv);
  }
}

// ============================================================================
// dec2_fused: ConvT 128ch -> 64ch + fused stats + vectorized epilogue.
// Output tile transposed in Bs (pixel pitch 68 halfs): full 128-px rows
// become contiguous half8 stores.
// ============================================================================
__global__ __launch_bounds__(256) void dec2_fused(
    const _Float16* __restrict__ act, const _Float16* __restrict__ wB,
    const float* __restrict__ bias, _Float16* __restrict__ y,
    float* __restrict__ stats)
{
  __shared__ __align__(16) _Float16 As[4 * 1056];   // [kg4][slot 2*66][8]
  __shared__ __align__(16) _Float16 Bs[18432];      // weights, then output tile
  const int tid = threadIdx.x;
  const int n = blockIdx.x >> 6;
  const int R = blockIdx.x & 63;
  const int wv = tid >> 6, lane = tid & 63;
  const int fr = lane >> 4, fc = lane & 15;

  floatx4 acc[4][4] = {};   // [cls][b]

  for (int c5 = 0; c5 < 4; c5++) {
    __syncthreads();
    for (int i = tid; i < 528; i += 256) {
      int slot = i >> 2, q = i & 3;
      int hr = slot / 66, hc = slot - hr * 66;
      int grow = R + hr;
      half8 v = {};
      if (grow < 64 && hc < 64)
        v = *(const half8*)(act + (((size_t)(n * 64 + grow)) * 64 + hc) * 128 + c5 * 32 + q * 8);
      *(half8*)(As + q * 1056 + slot * 8) = v;
    }
    #pragma unroll
    for (int t = 0; t < 9; t++)
      *(half8*)(Bs + t * 2048 + tid * 8) =
          *(const half8*)(wB + (size_t)(t * 4 + c5) * 2048 + tid * 8);
    __syncthreads();
    #pragma unroll
    for (int t = 0; t < 9; t++) {
      const int ky = t / 3, kx = t % 3;
      const int dy = (ky == 0) ? 1 : 0, dx = (kx == 0) ? 1 : 0;
      const int cls = ((ky + 1) & 1) * 2 + ((kx + 1) & 1);
      half8 af = *(const half8*)(As + fr * 1056 + (dy * 66 + wv * 16 + fc + dx) * 8);
      #pragma unroll
      for (int b = 0; b < 4; b++) {
        half8 bf = *(const half8*)(Bs + t * 2048 + fr * 512 + (b * 16 + fc) * 8);
        acc[cls][b] = __builtin_amdgcn_mfma_f32_16x16x32_f16(af, bf, acc[cls][b], 0, 0, 0);
      }
    }
  }

  float bv[4];
  #pragma unroll
  for (int b = 0; b < 4; b++) bv[b] = bias[b * 16 + fc];
  float ssum[4] = {}, ssq[4] = {};
  __syncthreads();
  // output tile into Bs: [2 rows][128 px] pitch 68 halfs per pixel
  #pragma unroll
  for (int cls = 0; cls < 4; cls++) {
    int py = cls >> 1, px = cls & 1;
    #pragma unroll
    for (int b = 0; b < 4; b++) {
      #pragma unroll
      for (int rr = 0; rr < 4; rr++) {
        int ipx = wv * 16 + fr * 4 + rr;
        float val = acc[cls][b][rr] + bv[b];
        Bs[(py * 128 + 2 * ipx + px) * 68 + b * 16 + fc] = (_Float16)val;
        ssum[b] += val; ssq[b] += val * val;
      }
    }
  }
  __syncthreads();
  float2* red = (float2*)As;
  #pragma unroll
  for (int b = 0; b < 4; b++)
    red[(b * 16 + fc) * 16 + wv * 4 + fr] = make_float2(ssum[b], ssq[b]);
  #pragma unroll
  for (int i = 0; i < 8; i++) {
    int idx = i * 256 + tid;             // 2048 half8 = 2 rows x 128px x 64ch
    int row = idx >> 10, rem = idx & 1023;
    int px = rem >> 3, chg = rem & 7;
    half8 v = *(const half8*)(Bs + (row * 128 + px) * 68 + chg * 8);
    *(half8*)(y + (((size_t)(n * 128 + 2 * R + row)) * 128 + px) * 64 + chg * 8) = v;
  }
  __syncthreads();
  if (tid < 64) {
    float s = 0.f, qv = 0.f;
    #pragma unroll
    for (int g2 = 0; g2 < 16; g2++) { float2 v = red[tid * 16 + g2]; s += v.x; qv += v.y; }
    int slot = blockIdx.x & (STAT_SLOTS - 1);
    float* sp = stats + ((size_t)tid * STAT_SLOTS + slot) * 2;
    atomicAdd(sp, s); atomicAdd(sp + 1, qv);
  }
}

// ============================================================================
// dec3_fused: ConvT 64ch -> 4ch + fused stats + vectorized epilogue
// (output tile in Bs: [4 rows][256px*4ch] pitch 1032; full-row half8 stores).
// ============================================================================
__global__ __launch_bounds__(256) void dec3_fused(
    const _Float16* __restrict__ act, const _Float16* __restrict__ wB,
    const float* __restrict__ bias, _Float16* __restrict__ y,
    float* __restrict__ stats)
{
  __shared__ __align__(16) _Float16 As[4 * 3168];
  __shared__ __align__(16) _Float16 Bs[9216];
  const int tid = threadIdx.x;
  const int n = blockIdx.x >> 6;
  const int y0 = (blockIdx.x & 63) << 1;
  const int wv = tid >> 6, lane = tid & 63;
  const int fr = lane >> 4, fc = lane & 15;

  for (int i = tid; i < 1152; i += 256)
    *(half8*)(Bs + i * 8) = *(const half8*)(wB + i * 8);

  floatx4 acc[4][4] = {};

  for (int c5 = 0; c5 < 2; c5++) {
    __syncthreads();
    for (int i = tid; i < 1584; i += 256) {
      int slot = i >> 2, q = i & 3;
      int prow = slot / 132, pcol = slot - prow * 132;
      int row = y0 + prow;
      half8 v = {};
      if (row < 128 && pcol < 128)
        v = *(const half8*)(act + (((size_t)(n * 128 + row)) * 128 + pcol) * 64 + c5 * 32 + q * 8);
      *(half8*)(As + q * 3168 + slot * 8) = v;
    }
    __syncthreads();
    #pragma unroll
    for (int t = 0; t < 9; t++) {
      const int ky = t / 3, kx = t % 3;
      const int dy = (ky == 0) ? 1 : 0, dx = (kx == 0) ? 1 : 0;
      const int cls = ((ky + 1) & 1) * 2 + ((kx + 1) & 1);
      half8 bf = *(const half8*)(Bs + (t * 2 + c5) * 512 + fr * 128 + fc * 8);
      #pragma unroll
      for (int a = 0; a < 4; a++) {
        int m = wv * 64 + a * 16 + fc;
        int r = m >> 7, xx = m & 127;
        half8 af = *(const half8*)(As + fr * 3168 + ((r + dy) * 132 + xx + dx) * 8);
        acc[cls][a] = __builtin_amdgcn_mfma_f32_16x16x32_f16(af, bf, acc[cls][a], 0, 0, 0);
      }
    }
  }

  float bv = (fc < 3) ? bias[fc] : 0.f;
  float s4 = 0.f, q4 = 0.f;
  __syncthreads();
  // output tile into Bs: [4 local rows][256 px][4 ch], row pitch 1032 halfs
  if (fc < 4) {
    #pragma unroll
    for (int cls = 0; cls < 4; cls++) {
      int py = cls >> 1, px = cls & 1;
      #pragma unroll
      for (int a = 0; a < 4; a++) {
        #pragma unroll
        for (int rr = 0; rr < 4; rr++) {
          int m = wv * 64 + a * 16 + fr * 4 + rr;
          int r = m >> 7, xx = m & 127;
          float val = acc[cls][a][rr] + bv;
          Bs[(r * 2 + py) * 1032 + (xx * 2 + px) * 4 + fc] = (_Float16)val;
          s4 += val; q4 += val * val;
        }
      }
    }
  }
  __syncthreads();
  float2* red = (float2*)As;
  if (fc < 4) red[fc * 16 + wv * 4 + fr] = make_float2(s4, q4);
  #pragma unroll
  for (int i = 0; i < 2; i++) {
    int idx = i * 256 + tid;            // 512 half8 = 4 rows x 1024 halfs
    int row = idx >> 7, grp = idx & 127;
    half8 v = *(const half8*)(Bs + row * 1032 + grp * 8);
    *(half8*)(y + (((size_t)(n * 256 + y0 * 2 + row)) * 256) * 4 + grp * 8) = v;
  }
  __syncthreads();
  if (tid < 4) {
    float s = 0.f, qv = 0.f;
    #pragma unroll
    for (int g2 = 0; g2 < 16; g2++) { float2 v = red[tid * 16 + g2]; s += v.x; qv += v.y; }
    int slot = blockIdx.x & (STAT_SLOTS - 1);
    float* sp = stats + ((size_t)tid * STAT_SLOTS + slot) * 2;
    atomicAdd(sp, s); atomicAdd(sp + 1, qv);
  }
}

// ============================================================================
// VQ GEMM
// ============================================================================
__global__ __launch_bounds__(256) void vq_gemm(const _Float16* __restrict__ h,
    const _Float16* __restrict__ embB, const float* __restrict__ ee,
    float* __restrict__ minval, int* __restrict__ minidx)
{
  __shared__ char smem[32768];
  _Float16* As = (_Float16*)smem;
  _Float16* Bs = (_Float16*)(smem + 8448);
  const int tid = threadIdx.x;
  const int m0 = blockIdx.x * 128, n0 = blockIdx.y * 128;
  const int q = tid & 3, r0 = tid >> 2;
  floatx4 acc[4][4] = {};
  const int wv = tid >> 6, lane = tid & 63;
  const int wm = wv >> 1, wn = wv & 1;
  const int fr = lane >> 4, fc = lane & 15;

  for (int c5 = 0; c5 < 16; c5++) {
    #pragma unroll
    for (int i = 0; i < 2; i++) {
      half8 v = *(const half8*)(h + (size_t)(m0 + r0 + i * 64) * 512 + c5 * 32 + q * 8);
      *(half8*)(As + q * 1032 + (r0 + i * 64) * 8) = v;
    }
    #pragma unroll
    for (int j = 0; j < 2; j++)
      *(half8*)(Bs + j * 2048 + tid * 8) =
          *(const half8*)(embB + (size_t)(c5 * 32 + (n0 >> 6) + j) * 2048 + tid * 8);
    __syncthreads();
    half8 af[4], bf[4];
    #pragma unroll
    for (int a = 0; a < 4; a++)
      af[a] = *(const half8*)(As + fr * 1032 + (wm * 64 + a * 16 + fc) * 8);
    #pragma unroll
    for (int b = 0; b < 4; b++) {
      int col = wn * 64 + b * 16 + fc;
      bf[b] = *(const half8*)(Bs + (col >> 6) * 2048 + fr * 512 + (col & 63) * 8);
    }
    #pragma unroll
    for (int a = 0; a < 4; a++)
      #pragma unroll
      for (int b = 0; b < 4; b++)
        acc[a][b] = __builtin_amdgcn_mfma_f32_16x16x32_f16(af[a], bf[b], acc[a][b], 0, 0, 0);
    __syncthreads();
  }

  float* sval = (float*)smem;
  int*   sidx = (int*)(smem + 16384);
  #pragma unroll
  for (int a = 0; a < 4; a++) {
    #pragma unroll
    for (int rr = 0; rr < 4; rr++) {
      int rb = wm * 64 + a * 16 + fr * 4 + rr;
      float best = 1e30f; int bi = 0;
      #pragma unroll
      for (int b = 0; b < 4; b++) {
        int e = n0 + wn * 64 + b * 16 + fc;
        float s = ee[e] - 2.f * acc[a][b][rr];
        if (s < best) { best = s; bi = e; }
      }
      sval[rb * 32 + wn * 16 + fc] = best;
      sidx[rb * 32 + wn * 16 + fc] = bi;
    }
  }
  __syncthreads();
  if (tid < 128) {
    float best = sval[tid * 32]; int bi = sidx[tid * 32];
    for (int t = 1; t < 32; t++) {
      float v = sval[tid * 32 + t]; int ix = sidx[tid * 32 + t];
      if (v < best || (v == best && ix < bi)) { best = v; bi = ix; }
    }
    minval[(size_t)(m0 + tid) * 16 + blockIdx.y] = best;
    minidx[(size_t)(m0 + tid) * 16 + blockIdx.y] = bi;
  }
}

__global__ __launch_bounds__(256) void vq_finalize(const _Float16* __restrict__ h,
    const float* __restrict__ emb, const float* __restrict__ minval,
    const int* __restrict__ minidx, float* __restrict__ lossacc)
{
  const int tid = threadIdx.x;
  const int g = tid >> 4, l = tid & 15;
  const int v = blockIdx.x * 16 + g;
  float val = minval[(size_t)v * 16 + l];
  int   idx = minidx[(size_t)v * 16 + l];
  #pragma unroll
  for (int o = 8; o > 0; o >>= 1) {
    float v2 = __shfl_down(val, o, 16);
    int   i2 = __shfl_down(idx, o, 16);
    if (v2 < val || (v2 == val && i2 < idx)) { val = v2; idx = i2; }
  }
  idx = __shfl(idx, 0, 16);
  float s = 0.f;
  #pragma unroll
  for (int j = 0; j < 32; j++) {
    int c = l + 16 * j;
    float f = (float)h[(size_t)v * 512 + c];
    float e = emb[(size_t)idx * 512 + c];
    float dd = f - e;
    s += dd * dd;
  }
  #pragma unroll
  for (int o = 8; o > 0; o >>= 1) s += __shfl_down(s, o, 16);
  if (l == 0) atomicAdd(lossacc, s);
}

// ============================================================================
// BN apply with inline scale/shift derivation from fused stats
// ============================================================================
__global__ __launch_bounds__(256) void bn_apply_inline(_Float16* __restrict__ y,
    const float2* __restrict__ stats, const float* __restrict__ g,
    const float* __restrict__ be, int Cs, int n8, float invM)
{
  const int C = 1 << Cs;
  __shared__ float scs[512], shs[512];
  for (int c = threadIdx.x; c < C; c += 256) {
    float s = 0.f, qv = 0.f;
    #pragma unroll
    for (int t = 0; t < STAT_SLOTS; t++) { float2 v = stats[c * STAT_SLOTS + t]; s += v.x; qv += v.y; }
    float m = s * invM, var = qv * invM - m * m;
    float sc = g[c] * rsqrtf(var + 1e-5f);
    scs[c] = sc; shs[c] = be[c] - m * sc;
  }
  __syncthreads();
  int i = blockIdx.x * 256 + threadIdx.x;
  if (i >= n8) return;
  int c0 = (i << 3) & (C - 1);
  half8 v = *(half8*)(y + (size_t)i * 8);
  half8 o;
  #pragma unroll
  for (int j = 0; j < 8; j++) {
    float x = (float)v[j] * scs[c0 + j] + shs[c0 + j];
    o[j] = (_Float16)(0.5f * x * (1.f + erff(x * 0.70710678118654752f)));
  }
  *(half8*)(y + (size_t)i * 8) = o;
}

__global__ __launch_bounds__(256) void bn_final_inline(const _Float16* __restrict__ y,
    float* __restrict__ out, const float2* __restrict__ stats,
    const float* __restrict__ g, const float* __restrict__ be,
    const float* __restrict__ lossacc)
{
  __shared__ float scs[4], shs[4];
  if (threadIdx.x < 3) {
    int c = threadIdx.x;
    float s = 0.f, qv = 0.f;
    #pragma unroll
    for (int t = 0; t < STAT_SLOTS; t++) { float2 v = stats[c * STAT_SLOTS + t]; s += v.x; qv += v.y; }
    const float invM = 1.f / 1048576.f;
    float m = s * invM, var = qv * invM - m * m;
    float sc = g[c] * rsqrtf(var + 1e-5f);
    scs[c] = sc; shs[c] = be[c] - m * sc;
  }
  __syncthreads();
  int p = blockIdx.x * 256 + threadIdx.x;
  int n = p >> 16, hw = p & 65535;
  half4t v = *(const half4t*)(y + (size_t)p * 4);
  #pragma unroll
  for (int c = 0; c < 3; c++) {
    float x = (float)v[c] * scs[c] + shs[c];
    float gg = 0.5f * x * (1.f + erff(x * 0.70710678118654752f));
    out[(size_t)(n * 3 + c) * 65536 + hw] = tanhf(gg);
  }
  if (p == 0) out[3145728] = lossacc[0] * (1.25f / 2097152.0f);
}

// ============================================================================
// prep_all: single kernel for every once-per-launch transform.
// ============================================================================
struct PrepPtrs {
  const float *ew0, *ew1, *ew2, *ew3, *dw0, *dw1, *dw2, *dw3, *emb, *x;
  _Float16 *wbE0, *wbE1, *wbE2, *wbE3, *wbD0, *wbD1, *wbD2, *wbD3, *embB, *xp;
  float *ee, *stats;
};

__device__ __forceinline__ void wtrans_g(const float* __restrict__ w,
    _Float16* __restrict__ wB, int CIs, int CI_real, int COs, int CO_real,
    int is_dec, int idx)
{
  int CO_pad = 1 << COs;
  int k = idx >> COs, co = idx & (CO_pad - 1);
  int tap = k >> CIs, ci = k & ((1 << CIs) - 1);
  int kh = tap / 3, kw = tap - kh * 3;
  float v = 0.f;
  if (ci < CI_real && co < CO_real)
    v = is_dec ? w[(((size_t)ci * CO_real + co) * 3 + kh) * 3 + kw]
               : w[(((size_t)co * CI_real + ci) * 3 + kh) * 3 + kw];
  int kt = k >> 5, kg = (k >> 3) & 3, kj = k & 7, jt = co >> 6, cc = co & 63;
  wB[(size_t)(kt * (CO_pad >> 6) + jt) * 2048 + kg * 512 + cc * 8 + kj] = (_Float16)v;
}

__global__ __launch_bounds__(256) void prep_all(PrepPtrs P)
{
  const int b = blockIdx.x;
  const int tid = threadIdx.x;
  if (b < 8) {
    int idx = b * 256 + tid;
    int k = idx >> 6, co = idx & 63;
    int tap = k / 3, c = k - tap * 3;
    float v = (k < 27) ? P.ew0[((size_t)co * 3 + c) * 9 + tap] : 0.f;
    int kg = (k >> 3) & 3, kj = k & 7;
    P.wbE0[kg * 512 + co * 8 + kj] = (_Float16)v;
  } else if (b < 296) {
    wtrans_g(P.ew1, P.wbE1, 6, 64, 7, 128, 0, (b - 8) * 256 + tid);
  } else if (b < 1448) {
    wtrans_g(P.ew2, P.wbE2, 7, 128, 8, 256, 0, (b - 296) * 256 + tid);
  } else if (b < 6056) {
    wtrans_g(P.ew3, P.wbE3, 8, 256, 9, 512, 0, (b - 1448) * 256 + tid);
  } else if (b < 10664) {
    wtrans_g(P.dw0, P.wbD0, 9, 512, 8, 256, 1, (b - 6056) * 256 + tid);
  } else if (b < 11816) {
    wtrans_g(P.dw1, P.wbD1, 8, 256, 7, 128, 1, (b - 10664) * 256 + tid);
  } else if (b < 12104) {
    wtrans_g(P.dw2, P.wbD2, 7, 128, 6, 64, 1, (b - 11816) * 256 + tid);
  } else if (b < 12140) {
    int idx = (b - 12104) * 256 + tid;
    int k = idx >> 4, co = idx & 15;
    int tap = k >> 6, ci = k & 63;
    float v = 0.f;
    if (co < 3) v = P.dw3[((size_t)ci * 3 + co) * 9 + tap];
    int kt = k >> 5, kg = (k >> 3) & 3, kj = k & 7;
    P.wbD3[(size_t)kt * 512 + kg * 128 + co * 8 + kj] = (_Float16)v;
  } else if (b < 16236) {
    int idx = (b - 12140) * 256 + tid;
    int k = idx >> 11, e = idx & 2047;
    float v = P.emb[(size_t)e * 512 + k];
    int kt = k >> 5, kg = (k >> 3) & 3, kj = k & 7, jt = e >> 6, cc = e & 63;
    P.embB[(size_t)(kt * 32 + jt) * 2048 + kg * 512 + cc * 8 + kj] = (_Float16)v;
  } else if (b < 16749) {
    int i = (b - 16236) * 256 + tid;
    if (i < 131073) P.stats[i] = 0.f;
  } else if (b < 17261) {
    int wv = tid >> 6, lane = tid & 63;
    int e = (b - 16749) * 4 + wv;
    float s = 0.f;
    #pragma unroll
    for (int j = 0; j < 8; j++) { float v = P.emb[(size_t)e * 512 + lane + j * 64]; s += v * v; }
    for (int o = 32; o > 0; o >>= 1) s += __shfl_down(s, o);
    if (lane == 0) P.ee[e] = s;
  } else {
    int p = (b - 17261) * 256 + tid;
    int n = p >> 14, oy = (p >> 7) & 127, ox = p & 127;
    const float* xb = P.x + (size_t)n * 3 * 65536;
    _Float16 v[32];
    #pragma unroll
    for (int k = 27; k < 32; k++) v[k] = (_Float16)0.f;
    #pragma unroll
    for (int tap = 0; tap < 9; tap++) {
      int kh = tap / 3, kw = tap - kh * 3;
      int ih = 2 * oy - 1 + kh, iw = 2 * ox - 1 + kw;
      bool ok = ((unsigned)ih < 256u) && ((unsigned)iw < 256u);
      #pragma unroll
      for (int c = 0; c < 3; c++)
        v[tap * 3 + c] = ok ? (_Float16)xb[(size_t)c * 65536 + ih * 256 + iw] : (_Float16)0.f;
    }
    _Float16* dst = P.xp + (size_t)p * 32;
    #pragma unroll
    for (int j = 0; j < 4; j++) *(half8*)(dst + j * 8) = *(half8*)(v + j * 8);
  }
}

// ============================================================================
// host
// ============================================================================
static ConvDesc enc_desc(int HI, int WI, int CIs, int CO) {
  ConvDesc d = {};
  d.HI = HI; d.WI = WI; d.CIs = CIs;
  int HO = HI / 2, WO = WI / 2;
  d.OYs = __builtin_ctz(HO); d.OXs = __builtin_ctz(WO);
  d.SXY = 2; d.osxy = 1; d.HO = HO; d.WO = WO;
  d.CO_pad = CO; d.CO_real = CO; d.CO_store = CO;
  d.nclass = 1; d.py[0] = 0; d.px[0] = 0; d.nt[0] = 9;
  for (int t = 0; t < 9; t++) { d.tt[0][t] = t; d.tdy[0][t] = t / 3 - 1; d.tdx[0][t] = t % 3 - 1; }
  return d;
}

static ConvDesc dec_desc(int HI, int WI, int CIs, int CO_pad, int CO_real, int CO_store) {
  ConvDesc d = {};
  d.HI = HI; d.WI = WI; d.CIs = CIs;
  d.OYs = __builtin_ctz(HI); d.OXs = __builtin_ctz(WI);
  d.SXY = 1; d.osxy = 2; d.HO = 2 * HI; d.WO = 2 * WI;
  d.CO_pad = CO_pad; d.CO_real = CO_real; d.CO_store = CO_store;
  d.nclass = 4;
  int kys[2][2] = {{1, -1}, {0, 2}}, dis[2][2] = {{0, -1}, {1, 0}}, cnt[2] = {1, 2};
  for (int py = 0; py < 2; py++)
    for (int px = 0; px < 2; px++) {
      int c = py * 2 + px; d.py[c] = py; d.px[c] = px;
      int m = 0;
      for (int a = 0; a < cnt[py]; a++)
        for (int b = 0; b < cnt[px]; b++) {
          d.tt[c][m] = kys[py][a] * 3 + kys[px][b];
          d.tdy[c][m] = dis[py][a]; d.tdx[c][m] = dis[px][b]; m++;
        }
      d.nt[c] = m;
    }
  return d;
}

extern "C" void kernel_launch(void* const* d_in, const int* in_sizes, int n_in,
                              void* d_out, int out_size, void* d_ws, size_t ws_size,
                              hipStream_t stream)
{
  const float* x = (const float*)d_in[0];
  const float *ew[4], *ebi[4], *eg[4], *ebe[4];
  const float *dw[4], *dbi[4], *dg[4], *dbe[4];
  for (int i = 0; i < 4; i++) {
    ew[i]  = (const float*)d_in[1 + 4 * i];
    ebi[i] = (const float*)d_in[2 + 4 * i];
    eg[i]  = (const float*)d_in[3 + 4 * i];
    ebe[i] = (const float*)d_in[4 + 4 * i];
    dw[i]  = (const float*)d_in[17 + 4 * i];
    dbi[i] = (const float*)d_in[18 + 4 * i];
    dg[i]  = (const float*)d_in[19 + 4 * i];
    dbe[i] = (const float*)d_in[20 + 4 * i];
  }
  const float* emb = (const float*)d_in[33];
  float* out = (float*)d_out;
  _Float16* wsh = (_Float16*)d_ws;

  // memory map (halfs)
  _Float16* bufA = wsh;
  _Float16* xp   = wsh;
  _Float16* bufB = wsh + 33554432;
  size_t wboff = 50331648;
  _Float16* wbE[4], *wbD[4];
  size_t wbsz[8] = {18432, 73728, 294912, 1179648, 1179648, 294912, 73728, 36864};
  for (int i = 0; i < 4; i++) { wbE[i] = wsh + wboff; wboff += wbsz[i]; }
  for (int i = 0; i < 4; i++) { wbD[i] = wsh + wboff; wboff += wbsz[4 + i]; }
  _Float16* embB = wsh + wboff;               // ends 54,532,096
  float* f32 = (float*)(wsh + 54532096);
  float* statsAll = f32;                      // 8 x 16384 floats
  float* lossacc  = f32 + 131072;
  float* ee       = f32 + 131080;
  float* minval   = f32 + 133128;
  int*   minidx   = (int*)(f32 + 198664);
  auto statsL = [&](int i) { return statsAll + (size_t)i * 16384; };

  // ---- single prep kernel ----
  PrepPtrs P;
  P.ew0 = ew[0]; P.ew1 = ew[1]; P.ew2 = ew[2]; P.ew3 = ew[3];
  P.dw0 = dw[0]; P.dw1 = dw[1]; P.dw2 = dw[2]; P.dw3 = dw[3];
  P.emb = emb; P.x = x;
  P.wbE0 = wbE[0]; P.wbE1 = wbE[1]; P.wbE2 = wbE[2]; P.wbE3 = wbE[3];
  P.wbD0 = wbD[0]; P.wbD1 = wbD[1]; P.wbD2 = wbD[2]; P.wbD3 = wbD[3];
  P.embB = embB; P.xp = xp; P.ee = ee; P.stats = statsAll;
  prep_all<<<18285, 256, 0, stream>>>(P);

  // ---- encoder ----
  {
    ConvDesc d = {};
    d.HI = 512; d.WI = 512; d.CIs = 5; d.OYs = 9; d.OXs = 9; d.SXY = 1; d.osxy = 1;
    d.HO = 512; d.WO = 512; d.CO_pad = 64; d.CO_real = 64; d.CO_store = 64;
    d.nclass = 1; d.nt[0] = 1;
    conv_gemm<128, 64><<<dim3(2048, 1, 1), 256, 0, stream>>>(xp, wbE[0], ebi[0], bufB, statsL(0), d);
    bn_apply_inline<<<8192, 256, 0, stream>>>(bufB, (const float2*)statsL(0), eg[0], ebe[0], 6, 2097152, 1.f / 262144.f);
  }
  {
    ConvDesc d = enc_desc(128, 128, 6, 128);
    conv_gemm<128, 128><<<dim3(512, 1, 1), 256, 0, stream>>>(bufB, wbE[1], ebi[1], bufA, statsL(1), d);
    bn_apply_inline<<<4096, 256, 0, stream>>>(bufA, (const float2*)statsL(1), eg[1], ebe[1], 7, 1048576, 1.f / 65536.f);
  }
  {
    ConvDesc d = enc_desc(64, 64, 7, 256);
    conv_gemm<128, 64><<<dim3(128, 4, 1), 256, 0, stream>>>(bufA, wbE[2], ebi[2], bufB, statsL(2), d);
    bn_apply_inline<<<2048, 256, 0, stream>>>(bufB, (const float2*)statsL(2), eg[2], ebe[2], 8, 524288, 1.f / 16384.f);
  }
  {
    ConvDesc d = enc_desc(32, 32, 8, 512);
    conv_gemm<64, 64><<<dim3(64, 8, 1), 256, 0, stream>>>(bufB, wbE[3], ebi[3], bufA, statsL(3), d);
    bn_apply_inline<<<1024, 256, 0, stream>>>(bufA, (const float2*)statsL(3), eg[3], ebe[3], 9, 262144, 1.f / 4096.f);
  }
  _Float16* h = bufA;  // (16,16,16,512) NHWC

  // ---- VQ ----
  vq_gemm<<<dim3(32, 16), 256, 0, stream>>>(h, embB, ee, minval, minidx);
  vq_finalize<<<256, 256, 0, stream>>>(h, emb, minval, minidx, lossacc);

  // ---- decoder ----
  {
    ConvDesc d = dec_desc(16, 16, 9, 256, 256, 256);
    conv_gemm<64, 64><<<dim3(64, 4, 4), 256, 0, stream>>>(h, wbD[0], dbi[0], bufB, statsL(4), d);
    bn_apply_inline<<<2048, 256, 0, stream>>>(bufB, (const float2*)statsL(4), dg[0], dbe[0], 8, 524288, 1.f / 16384.f);
  }
  {
    ConvDesc d = dec_desc(32, 32, 8, 128, 128, 128);
    conv_gemm<128, 128><<<dim3(128, 1, 4), 256, 0, stream>>>(bufB, wbD[1], dbi[1], bufA, statsL(5), d);
    bn_apply_inline<<<4096, 256, 0, stream>>>(bufA, (const float2*)statsL(5), dg[1], dbe[1], 7, 1048576, 1.f / 65536.f);
  }
  {
    dec2_fused<<<1024, 256, 0, stream>>>(bufA, wbD[2], dbi[2], bufB, statsL(6));
    bn_apply_inline<<<8192, 256, 0, stream>>>(bufB, (const float2*)statsL(6), dg[2], dbe[2], 6, 2097152, 1.f / 262144.f);
  }
  {
    dec3_fused<<<1024, 256, 0, stream>>>(bufB, wbD[3], dbi[3], bufA, statsL(7));
    bn_final_inline<<<4096, 256, 0, stream>>>(bufA, out, (const float2*)statsL(7), dg[3], dbe[3], lossacc);
  }
}